// Round 4
// baseline (1538.252 us; speedup 1.0000x reference)
//
#include <hip/hip_runtime.h>

typedef unsigned short u16;
typedef unsigned int u32;
typedef __attribute__((ext_vector_type(8))) __bf16 bf16x8;
typedef __attribute__((ext_vector_type(4))) float f32x4;

#define D_ 1024
#define H_ 4096
#define E_ 8
#define NT_ 4096          // B*T tokens
#define RCAP_ 8704        // 8192 routed rows + pad-to-8 + 256-row tile over-read slack
#define CAPX_ 12800       // NT_ (shared token rows) + RCAP_ (routed rows), unified row space

#define LDSH_ 8192        // u16 per half-tile (128 rows x 64)
#define LDST_ 16384       // u16 per tile buffer (256 rows x 64)

// Packed operand layout (all GEMM inputs): P[k>>6][row][64] bf16, XOR swizzle baked
// per row: element (k&63) stored at ((((k&63)>>3) ^ (row&7))<<3) | (k&7).
// -> staging a 256x64 tile is 32KB contiguous; ds_read_b128 with matching XOR = 0 conflicts (r2-verified).

// ---------- helpers ----------
__device__ __forceinline__ u16 f2b(float f) {   // fp32 -> bf16 bits, RNE
  u32 u = __float_as_uint(f);
  u += 0x7fffu + ((u >> 16) & 1u);
  return (u16)(u >> 16);
}

__device__ __forceinline__ void glds16(const u16* g, u16* l) {
  __builtin_amdgcn_global_load_lds((const __attribute__((address_space(1))) void*)g,
                                   (__attribute__((address_space(3))) void*)l, 16, 0, 0);
}

__device__ __forceinline__ void stage_half(const u16* __restrict__ g, u16* l, int wv, int lane) {
#pragma unroll
  for (int c = 0; c < 2; ++c)
    glds16(g + c * 4096 + wv * 512 + lane * 8, l + c * 4096 + wv * 512);
}

// stage one full 256x64 tile for A and B: 8 glds16 per wave (64KB total)
__device__ __forceinline__ void stage_tile(const u16* __restrict__ ga, const u16* __restrict__ gb,
                                           u16* la, u16* lb, int wv, int lane) {
  stage_half(ga,         la,         wv, lane);
  stage_half(ga + LDSH_, la + LDSH_, wv, lane);
  stage_half(gb,         lb,         wv, lane);
  stage_half(gb + LDSH_, lb + LDSH_, wv, lane);
}

// ---------- small kernels ----------
__global__ void init_ints(int* p, int n) {
  int i = threadIdx.x;
  if (i < n) p[i] = 0;
}

__global__ void zero_f32(float* __restrict__ p) {
  ((float4*)p)[blockIdx.x * 256 + threadIdx.x] = make_float4(0.f, 0.f, 0.f, 0.f);
}

// x [NT][D] f32 -> XC rows [0,NT) packed [D/64][CAPX][64] bf16 (swizzled by token&7)
__global__ void pack_x(const float* __restrict__ x, u16* __restrict__ xc) {
  const int t = blockIdx.x, i = threadIdx.x;          // 256 threads, 4 f32 each
  float4 v = ((const float4*)(x + (size_t)t * D_))[i];
  const int kb = i >> 4, ch = (i >> 1) & 7, sub = (i & 1) * 4;
  u16 tmp[4] = {f2b(v.x), f2b(v.y), f2b(v.z), f2b(v.w)};
  *(uint2*)(xc + ((size_t)kb * CAPX_ + t) * 64 + ((ch ^ (t & 7)) << 3) + sub) = *(uint2*)tmp;
}

// src [Z][Kdim][Rdim] f32 (+optional src2 for gu-interleave) -> dst [Z][Kdim/64][Rout][64] bf16
__global__ void pack_b(const float* __restrict__ src, const float* __restrict__ src2,
                       u16* __restrict__ dst, int Kdim, int Rdim) {
  const int r0 = blockIdx.x * 64, k0 = blockIdx.y * 64, z = blockIdx.z;
  const int Rout = src2 ? (Rdim * 2) : Rdim;
  src += (size_t)z * Kdim * Rdim;
  if (src2) src2 += (size_t)z * Kdim * Rdim;
  u16* dkb = dst + (size_t)z * (Kdim >> 6) * Rout * 64 + (size_t)(k0 >> 6) * Rout * 64;
  __shared__ float t1[64][65];
  __shared__ float t2[64][65];
  const int tx = threadIdx.x, ty = threadIdx.y;       // 64, 4
#pragma unroll
  for (int i = 0; i < 16; ++i) {
    const int kk = ty + 4 * i;
    t1[kk][tx] = src[(size_t)(k0 + kk) * Rdim + r0 + tx];
    if (src2) t2[kk][tx] = src2[(size_t)(k0 + kk) * Rdim + r0 + tx];
  }
  __syncthreads();
  const int idx = ty * 64 + tx;          // 0..255
  const int ch = idx & 7, rl0 = idx >> 3;
#pragma unroll
  for (int half = 0; half < 2; ++half) {
    const int rl = rl0 + 32 * half;      // 0..63
    const int r = r0 + rl;
    if (src2) {
      const int rg = 32 * (r >> 4) + (r & 15), ru = rg + 16;
      const int kg = (ch ^ (rg & 7)) << 3;   // rg&7 == ru&7 == r&7
      union { u16 v[8]; uint4 q; } pg, pu;
#pragma unroll
      for (int j = 0; j < 8; ++j) pg.v[j] = f2b(t1[kg + j][rl]);
#pragma unroll
      for (int j = 0; j < 8; ++j) pu.v[j] = f2b(t2[kg + j][rl]);
      *(uint4*)(dkb + (size_t)rg * 64 + ch * 8) = pg.q;
      *(uint4*)(dkb + (size_t)ru * 64 + ch * 8) = pu.q;
    } else {
      const int kc = (ch ^ (r & 7)) << 3;
      union { u16 v[8]; uint4 q; } pk;
#pragma unroll
      for (int j = 0; j < 8; ++j) pk.v[j] = f2b(t1[kc + j][rl]);
      *(uint4*)(dkb + (size_t)r * 64 + ch * 8) = pk.q;
    }
  }
}

// fp32 noisy top-2 router: one wave per token
__global__ void router_k(const float* __restrict__ x, const float* __restrict__ noise,
                         const float* __restrict__ Wr, const float* __restrict__ br,
                         const float* __restrict__ Wn, const float* __restrict__ bn,
                         int* __restrict__ counts, int* __restrict__ tok_e,
                         float* __restrict__ tok_g) {
  const int t = blockIdx.x;
  const int lane = threadIdx.x;
  float xv[16];
#pragma unroll
  for (int i = 0; i < 16; ++i) xv[i] = x[(size_t)t * D_ + lane + 64 * i];
  float nz[E_];
#pragma unroll
  for (int e = 0; e < E_; ++e) {
    float ar = 0.f, an = 0.f;
#pragma unroll
    for (int i = 0; i < 16; ++i) {
      int d = lane + 64 * i;
      ar += xv[i] * Wr[d * E_ + e];
      an += xv[i] * Wn[d * E_ + e];
    }
#pragma unroll
    for (int o = 32; o > 0; o >>= 1) {
      ar += __shfl_down(ar, o, 64);
      an += __shfl_down(an, o, 64);
    }
    if (lane == 0) {
      float lg = ar + br[e], nl = an + bn[e];
      float sp = (nl > 20.f) ? nl : log1pf(expf(nl));     // softplus
      nz[e] = lg + noise[(size_t)t * E_ + e] * sp;
    }
  }
  if (lane == 0) {
    int i0 = 0;
#pragma unroll
    for (int e = 1; e < E_; ++e) if (nz[e] > nz[i0]) i0 = e;
    int i1 = (i0 == 0) ? 1 : 0;
#pragma unroll
    for (int e = 0; e < E_; ++e) if (e != i0 && nz[e] > nz[i1]) i1 = e;
    float a = nz[i0], b = nz[i1];
    float m = fmaxf(a, b);
    float ea = expf(a - m), eb = expf(b - m);
    float inv = 1.f / (ea + eb);
    tok_e[2 * t] = i0; tok_e[2 * t + 1] = i1;
    tok_g[2 * t] = ea * inv; tok_g[2 * t + 1] = eb * inv;
    atomicAdd(&counts[i0], 1);
    atomicAdd(&counts[i1], 1);
  }
}

__global__ void scan_k(const int* __restrict__ counts, int* __restrict__ offsets) {
  if (threadIdx.x == 0) {
    int acc = 0;
    for (int e = 0; e < E_; ++e) { offsets[e] = acc; acc += (counts[e] + 7) & ~7; }
    offsets[E_] = acc;   // expert bases padded to 8 so the row-swizzle phase is uniform
  }
}

// gather token rows XC[t] -> XC rows [NT_+r); re-swizzle chunks from t&7 to r&7
__global__ void gather_k(const u16* __restrict__ xc, const int* __restrict__ tok_e,
                         const float* __restrict__ tok_g, const int* __restrict__ offsets,
                         int* __restrict__ cursors, u16* __restrict__ xcw,
                         int* __restrict__ row_token, float* __restrict__ row_gate) {
  const int t = blockIdx.x;
  __shared__ int rws[2];
  if (threadIdx.x < 2) {
    int e = tok_e[2 * t + threadIdx.x];
    int r = offsets[e] + atomicAdd(&cursors[e], 1);
    row_token[r] = t;
    row_gate[r] = tok_g[2 * t + threadIdx.x];
    rws[threadIdx.x] = r;
  }
  __syncthreads();
  const int r0 = rws[0], r1 = rws[1];
  const int x7 = t & 7;
#pragma unroll
  for (int it = 0; it < 2; ++it) {
    const int u = threadIdx.x + 64 * it;      // 0..127 : 16 kb x 8 chunks
    const int kb = u >> 3, cs = u & 7;
    uint4 v = *(const uint4*)(xc + ((size_t)kb * CAPX_ + t) * 64 + (cs << 3));
    const int c = cs ^ x7;
    *(uint4*)(xcw + ((size_t)kb * CAPX_ + NT_ + r0) * 64 + ((c ^ (r0 & 7)) << 3)) = v;
    *(uint4*)(xcw + ((size_t)kb * CAPX_ + NT_ + r1) * 64 + ((c ^ (r1 & 7)) << 3)) = v;
  }
}

// ---------- 256x256 8-wave GEMM core, wide-window staging (T3+T4+T5) ----------
// Per K-tile: 2 sub-phases (ks0/ks1), 4 barriers. Tile t+2 staged in ONE burst mid-ks1,
// into the current buffer (its reads were all issued before the mid-ks1 barrier).
// Tile boundary waits vmcnt(8): tile t+1 landed, tile t+2's 8 loads keep flying
// -> every load gets a ~1.5-K-tile landing window (r3's defect: B1 had ~1 phase).
__device__ __forceinline__ void gemm_core8(
    const u16* __restrict__ A, const u16* __restrict__ B,
    size_t aKS, size_t bKS, int NKB,
    u16* As, u16* Bs, f32x4 acc[8][4], int tid) {
  const int lane = tid & 63, wv = tid >> 6;
  const int wr = wv >> 2, wc = wv & 3;
  const int lm = lane & 15, lq = lane >> 4;
  const int c0 = ((lq ^ (lm & 7)) << 4);                   // swizzled chunk byte offset, ks0
  const char* asr = (const char*)As + (wr * 128 + lm) * 128;
  const char* bsr = (const char*)Bs + (wc * 64 + lm) * 128;

  // prologue: tiles 0 and 1 staged; wait tile0 (8), keep tile1's 8 flying
  stage_tile(A, B, As, Bs, wv, lane);
  stage_tile(A + aKS, B + bKS, As + LDST_, Bs + LDST_, wv, lane);
  asm volatile("s_waitcnt vmcnt(8)" ::: "memory");
  __builtin_amdgcn_s_barrier();
  __builtin_amdgcn_sched_barrier(0);

  for (int t = 0; t < NKB; ++t) {
    const int bu = (t & 1) * LDST_;          // u16 offset of current buf
    const int bo = bu * 2;                   // byte offset
    bf16x8 a[8], bb[4];
    // ---- ks0 ----
#pragma unroll
    for (int i = 0; i < 8; ++i)
      a[i] = *(const bf16x8*)(asr + bo + i * 2048 + c0);
#pragma unroll
    for (int j = 0; j < 4; ++j)
      bb[j] = *(const bf16x8*)(bsr + bo + j * 2048 + c0);
    asm volatile("s_waitcnt lgkmcnt(8)" ::: "memory");
    __builtin_amdgcn_s_barrier();
    asm volatile("s_waitcnt lgkmcnt(0)" ::: "memory");
    __builtin_amdgcn_sched_barrier(0);
    __builtin_amdgcn_s_setprio(1);
#pragma unroll
    for (int i = 0; i < 8; ++i)
#pragma unroll
      for (int j = 0; j < 4; ++j)
        acc[i][j] = __builtin_amdgcn_mfma_f32_16x16x32_bf16(a[i], bb[j], acc[i][j], 0, 0, 0);
    __builtin_amdgcn_s_setprio(0);
    __builtin_amdgcn_s_barrier();
    // ---- ks1 ----
#pragma unroll
    for (int i = 0; i < 8; ++i)
      a[i] = *(const bf16x8*)(asr + bo + i * 2048 + (c0 ^ 64));
#pragma unroll
    for (int j = 0; j < 4; ++j)
      bb[j] = *(const bf16x8*)(bsr + bo + j * 2048 + (c0 ^ 64));
    asm volatile("s_waitcnt lgkmcnt(8)" ::: "memory");
    __builtin_amdgcn_s_barrier();          // all waves issued their last reads of buf(t&1)
    asm volatile("s_waitcnt lgkmcnt(0)" ::: "memory");
    __builtin_amdgcn_sched_barrier(0);
    if (t + 2 < NKB)                       // stage tile t+2 into the freed current buffer
      stage_tile(A + (size_t)(t + 2) * aKS, B + (size_t)(t + 2) * bKS,
                 As + bu, Bs + bu, wv, lane);
    __builtin_amdgcn_s_setprio(1);
#pragma unroll
    for (int i = 0; i < 8; ++i)
#pragma unroll
      for (int j = 0; j < 4; ++j)
        acc[i][j] = __builtin_amdgcn_mfma_f32_16x16x32_bf16(a[i], bb[j], acc[i][j], 0, 0, 0);
    __builtin_amdgcn_s_setprio(0);
    if (t + 1 < NKB) {
      if (t + 2 < NKB) { asm volatile("s_waitcnt vmcnt(8)" ::: "memory"); }
      else             { asm volatile("s_waitcnt vmcnt(0)" ::: "memory"); }
      __builtin_amdgcn_sched_barrier(0);
      __builtin_amdgcn_s_barrier();
    }
  }
}

// ---------- GEMM1 merged (shared z=8 + routed experts), swiglu epilogue -> ACT packed ----------
// A = XC [D/64][CAPX][64]; Bgu [E][16][8192][64] gu-interleaved; Sgu [16][8192][64]
__global__ __launch_bounds__(512, 2)
void gemm1_k(const u16* __restrict__ XC, const u16* __restrict__ Wgup,
             const u16* __restrict__ Sgup, u16* __restrict__ ACT,
             const int* __restrict__ counts, const int* __restrict__ offsets) {
  const int lid = blockIdx.x;
  int rowbase, mrem, n0;
  const u16* B;
  if (lid < 4096) {          // routed: e = lid&7 == XCD (round-robin dispatch)
    const int e = lid & 7, bx = (lid >> 3) & 15, by = lid >> 7;
    const int ne = counts[e];
    if (bx * 256 >= ne) return;
    mrem = ne - bx * 256;
    rowbase = NT_ + offsets[e] + bx * 256;
    n0 = by * 256;
    B = Wgup + ((size_t)e * 16 * 8192 + n0) * 64;
  } else {                   // shared: bx&7 == XCD -> A-panel L2 locality
    const int s = lid - 4096, bx = s & 15, by = s >> 4;
    mrem = 256;
    rowbase = bx * 256;
    n0 = by * 256;
    B = Sgup + (size_t)n0 * 64;
  }
  const u16* A = XC + (size_t)rowbase * 64;

  __shared__ __align__(16) u16 As[2 * LDST_], Bs[2 * LDST_];
  f32x4 acc[8][4] = {};
  const int tid = threadIdx.x;
  gemm_core8(A, B, (size_t)CAPX_ * 64, (size_t)8192 * 64, D_ >> 6, As, Bs, acc, tid);

  // epilogue: j even = g, j odd = u; write ACT packed+swizzled
  const int lane = tid & 63, wv = tid >> 6;
  const int wr = wv >> 2, wc = wv & 3;
  const int lm = lane & 15, lq = lane >> 4;
  const int hb = (n0 + wc * 64) >> 1;
#pragma unroll
  for (int i = 0; i < 8; ++i)
#pragma unroll
    for (int q = 0; q < 4; ++q) {
      const int m = wr * 128 + i * 16 + lq * 4 + q;
      if (m < mrem) {
        const int row = rowbase + m;
        const int r7 = row & 7;
#pragma unroll
        for (int jj = 0; jj < 2; ++jj) {
          float g = acc[i][2 * jj][q], u = acc[i][2 * jj + 1][q];
          float s = g / (1.f + __expf(-g)) * u;
          const int h = hb + jj * 16 + lm;
          ACT[((size_t)(h >> 6) * CAPX_ + row) * 64 + ((((h >> 3) & 7) ^ r7) << 3 | (h & 7))] = f2b(s);
        }
      }
    }
}

// ---------- GEMM2 merged: out += gate * (ACT @ Wd) via atomics (out zero-initialized) ----------
// A = ACT [H/64][CAPX][64]; Wdp [E][64][1024][64]; Sdp [64][1024][64]
__global__ __launch_bounds__(512, 2)
void gemm2_k(const u16* __restrict__ ACT, const u16* __restrict__ Wdp,
             const u16* __restrict__ Sdp, float* __restrict__ out,
             const int* __restrict__ counts, const int* __restrict__ offsets,
             const int* __restrict__ row_token, const float* __restrict__ row_gate) {
  const int lid = blockIdx.x;
  int rowbase, mrem, n0;
  bool routed;
  const u16* B;
  if (lid < 512) {           // routed
    const int e = lid & 7, r = lid >> 3;
    const int bx = r & 15, by = r >> 4;
    const int ne = counts[e];
    if (bx * 256 >= ne) return;
    mrem = ne - bx * 256;
    rowbase = NT_ + offsets[e] + bx * 256;
    n0 = by * 256;
    B = Wdp + ((size_t)e * 64 * 1024 + n0) * 64;
    routed = true;
  } else {                   // shared
    const int s = lid - 512, bx = s & 15, by = s >> 4;
    mrem = 256;
    rowbase = bx * 256;
    n0 = by * 256;
    B = Sdp + (size_t)n0 * 64;
    routed = false;
  }
  const u16* A = ACT + (size_t)rowbase * 64;

  __shared__ __align__(16) u16 As[2 * LDST_], Bs[2 * LDST_];
  f32x4 acc[8][4] = {};
  const int tid = threadIdx.x;
  gemm_core8(A, B, (size_t)CAPX_ * 64, (size_t)1024 * 64, H_ >> 6, As, Bs, acc, tid);

  const int lane = tid & 63, wv = tid >> 6;
  const int wr = wv >> 2, wc = wv & 3;
  const int lm = lane & 15, lq = lane >> 4;
#pragma unroll
  for (int i = 0; i < 8; ++i)
#pragma unroll
    for (int q = 0; q < 4; ++q) {
      const int m = wr * 128 + i * 16 + lq * 4 + q;
      if (m < mrem) {
        const int rowAbs = rowbase + m;
        int tkn; float gt;
        if (routed) { const int idx = rowAbs - NT_; tkn = row_token[idx]; gt = row_gate[idx]; }
        else        { tkn = rowAbs; gt = 1.f; }
        const int n = n0 + wc * 64 + lm;
#pragma unroll
        for (int j = 0; j < 4; ++j)
          atomicAdd(out + (size_t)tkn * D_ + n + j * 16, gt * acc[i][j][q]);
      }
    }
}

// ---------- host ----------
extern "C" void kernel_launch(void* const* d_in, const int* in_sizes, int n_in,
                              void* d_out, int out_size, void* d_ws, size_t ws_size,
                              hipStream_t stream) {
  const float* x     = (const float*)d_in[0];
  const float* noise = (const float*)d_in[1];
  const float* Wr    = (const float*)d_in[2];
  const float* br    = (const float*)d_in[3];
  const float* Wn    = (const float*)d_in[4];
  const float* bn    = (const float*)d_in[5];
  const float* Wg    = (const float*)d_in[6];
  const float* Wu    = (const float*)d_in[7];
  const float* Wd    = (const float*)d_in[8];
  const float* Sg    = (const float*)d_in[9];
  const float* Su    = (const float*)d_in[10];
  const float* Sd    = (const float*)d_in[11];
  float* out = (float*)d_out;

  char* base = (char*)d_ws;
  size_t off = 0;
  auto take = [&](size_t bytes) -> void* {
    void* r = base + off;
    off = (off + bytes + 255) & ~(size_t)255;
    return r;
  };
  u16* Wgup = (u16*)take((size_t)E_ * 16 * 8192 * 64 * 2);  // [E][D/64][8192 gu][64]
  u16* Wdp  = (u16*)take((size_t)E_ * 64 * 1024 * 64 * 2);  // [E][H/64][1024][64]
  u16* Sgup = (u16*)take((size_t)16 * 8192 * 64 * 2);       // [D/64][8192 gu][64]
  u16* Sdp  = (u16*)take((size_t)64 * 1024 * 64 * 2);       // [H/64][1024][64]
  u16* XC   = (u16*)take((size_t)16 * CAPX_ * 64 * 2);      // [D/64][CAPX][64]
  u16* ACT  = (u16*)take((size_t)64 * CAPX_ * 64 * 2);      // [H/64][CAPX][64]
  int*   row_token = (int*)take(RCAP_ * 4);
  float* row_gate  = (float*)take(RCAP_ * 4);
  int*   tok_e = (int*)take(NT_ * 2 * 4);
  float* tok_g = (float*)take(NT_ * 2 * 4);
  int* ints = (int*)take(32 * 4);                    // counts[8] cursors[8] offsets[9]
  int* counts = ints, *cursors = ints + 8, *offsets = ints + 16;
  if (off > ws_size) return;   // ws too small: clean no-op fail

  hipLaunchKernelGGL(init_ints, dim3(1), dim3(64), 0, stream, ints, 32);
  hipLaunchKernelGGL(zero_f32, dim3(NT_ * D_ / 4 / 256), dim3(256), 0, stream, out);
  hipLaunchKernelGGL(pack_x, dim3(NT_), dim3(256), 0, stream, x, XC);
  dim3 tb(64, 4);
  hipLaunchKernelGGL(pack_b, dim3(H_ / 64, D_ / 64, E_), tb, 0, stream, Wg, Wu, Wgup, D_, H_);
  hipLaunchKernelGGL(pack_b, dim3(D_ / 64, H_ / 64, E_), tb, 0, stream,
                     Wd, (const float*)nullptr, Wdp, H_, D_);
  hipLaunchKernelGGL(pack_b, dim3(H_ / 64, D_ / 64, 1), tb, 0, stream, Sg, Su, Sgup, D_, H_);
  hipLaunchKernelGGL(pack_b, dim3(D_ / 64, H_ / 64, 1), tb, 0, stream,
                     Sd, (const float*)nullptr, Sdp, H_, D_);

  hipLaunchKernelGGL(router_k, dim3(NT_), dim3(64), 0, stream,
                     x, noise, Wr, br, Wn, bn, counts, tok_e, tok_g);
  hipLaunchKernelGGL(scan_k, dim3(1), dim3(64), 0, stream, counts, offsets);
  hipLaunchKernelGGL(gather_k, dim3(NT_), dim3(64), 0, stream,
                     XC, tok_e, tok_g, offsets, cursors, XC, row_token, row_gate);

  // merged gemm1 (routed lids [0,4096) + shared lids [4096,4608))
  hipLaunchKernelGGL(gemm1_k, dim3(4096 + 512), dim3(512), 0, stream,
                     XC, Wgup, Sgup, ACT, counts, offsets);
  // merged gemm2 (routed lids [0,512) + shared lids [512,576)); out zero-init'd, all-atomic
  hipLaunchKernelGGL(gemm2_k, dim3(512 + 64), dim3(512), 0, stream,
                     ACT, Wdp, Sdp, out, counts, offsets, row_token, row_gate);
}